// Round 2
// baseline (67.346 us; speedup 1.0000x reference)
//
#include <hip/hip_runtime.h>
#include <math.h>

// GraphPoolMol: B=64, MAX_ATOM=128, N_FEAT=128, fp32.
// out[b,i,f] = i<n ? max_{j<n, L[b,i,j]!=0} x[b,j,f] (fallback x[b,i,f]) : 0
//
// One wave (64 lanes) per output row. L-row nonzero mask built with two
// __ballot's (entries 2*lane, 2*lane+1) -> wave-uniform 64-bit scalars.
// Neighbor iteration = ctz over the scalar mask: no LDS, no barriers,
// no atomics; every global access is coalesced float2 (512 B/wave).

#define MAX_ATOM 128
#define N_FEAT 128
#define NBATCH 64

__global__ __launch_bounds__(256) void GraphPoolMol_kernel(
    const float* __restrict__ x,       // (B, MAX_ATOM, N_FEAT)
    const float* __restrict__ L,       // (B, MAX_ATOM, MAX_ATOM)
    const int* __restrict__ mol_slice, // (B, 2) col0 = n_atoms
    float* __restrict__ out)           // (B, MAX_ATOM, N_FEAT)
{
    const int lane = threadIdx.x & 63;
    const int wav  = threadIdx.x >> 6;
    const int i    = blockIdx.x * 4 + wav;  // atom row (wave-uniform)
    const int b    = blockIdx.y;            // batch

    const int n = mol_slice[b * 2];

    float2* orow = (float2*)(out + ((size_t)b * MAX_ATOM + i) * N_FEAT);

    if (i >= n) {                      // invalid row: zero-fill
        orow[lane] = make_float2(0.0f, 0.0f);
        return;
    }

    const float* __restrict__ xb = x + (size_t)b * MAX_ATOM * N_FEAT;
    const float2* __restrict__ Lrow2 =
        (const float2*)(L + ((size_t)b * MAX_ATOM + i) * MAX_ATOM);

    // Entries j0 = 2*lane, j1 = 2*lane+1 of the laplacian row.
    const float2 lv = Lrow2[lane];
    const int j0 = lane * 2;
    const int j1 = j0 + 1;
    const unsigned long long m0 = __ballot((lv.x != 0.0f) && (j0 < n));
    const unsigned long long m1 = __ballot((lv.y != 0.0f) && (j1 < n));

    float2 acc = make_float2(-INFINITY, -INFINITY);

    unsigned long long mm = m0;        // wave-uniform scalar loop
    while (mm) {
        const int l = __builtin_ctzll(mm);
        mm &= mm - 1;
        const float2* xr = (const float2*)(xb + (size_t)(2 * l) * N_FEAT);
        const float2 v = xr[lane];     // coalesced 512B row read
        acc.x = fmaxf(acc.x, v.x);
        acc.y = fmaxf(acc.y, v.y);
    }
    mm = m1;
    while (mm) {
        const int l = __builtin_ctzll(mm);
        mm &= mm - 1;
        const float2* xr = (const float2*)(xb + (size_t)(2 * l + 1) * N_FEAT);
        const float2 v = xr[lane];
        acc.x = fmaxf(acc.x, v.x);
        acc.y = fmaxf(acc.y, v.y);
    }

    if ((m0 | m1) == 0ull) {           // no-neighbor fallback (defensive;
        const float2* xr = (const float2*)(xb + (size_t)i * N_FEAT);
        acc = xr[lane];                //  diagonal=1 makes this unreachable)
    }

    orow[lane] = acc;
}

extern "C" void kernel_launch(void* const* d_in, const int* in_sizes, int n_in,
                              void* d_out, int out_size, void* d_ws, size_t ws_size,
                              hipStream_t stream) {
    const float* x   = (const float*)d_in[0];   // node_features
    const float* L   = (const float*)d_in[1];   // laplacian
    const int* mol   = (const int*)d_in[2];     // mol_slice
    float* out = (float*)d_out;

    dim3 grid(MAX_ATOM / 4, NBATCH);  // 32 x 64 blocks, 4 rows/block (1 wave each)
    dim3 block(256);
    GraphPoolMol_kernel<<<grid, block, 0, stream>>>(x, L, mol, out);
}